// Round 12
// baseline (1349.755 us; speedup 1.0000x reference)
//
#include <hip/hip_runtime.h>

// VQ-VAE VectorQuantizer forward, fp32, MI355X.
// B=64, C=D=64, H=W=32 -> N=65536 pixels, K=1024 codes.
// Outputs (flat concat): [0] loss, [1..4194305) quantized BCHW, [4194305..) indices (as float)
//
// R12: all-LDS loop — no scalar memory, no per-lane arrays.
// R4/R9/R10/R11 lesson: e-on-scalar tops at ~160-185us (needs SGPR staging ->
// lgkm drains, AND occupancy its footprint denies). Now: x [64d][64px]=16KB
// staged once; e per-wave double-buffered 8-code tiles (2KB) staged via
// coalesced float4 L2 loads (T14 split: LD t+2 / compute t / ST t+1),
// consumed as uniform-address ds_read_b128 broadcasts (conflict-free, imm
// offsets); esq staged to LDS (4KB). 256 thr = 4 waves/block, wave owns 256
// codes; ~38KB LDS, ~50 VGPR -> 4 blocks/CU, grid 1024 = exact packing.
// Per-code arithmetic BIT-IDENTICAL to R0-R11 (passed, absmax 3.8e-6):
// pairwise-8 x_sq (fp-contract off), sequential d-ascending fp32 FMA dot,
// dist = (x_sq - 2*dot) + e_sq, strict-< ascending-k argmin, ascending merge.

#define KCODES 1024
#define DDIM   64
#define NPIX   65536        // B*H*W
#define QELEMS 4194304      // B*C*H*W
#define IDX_OFF (1 + QELEMS)
#define NWAVE  4            // waves per block = K chunks
#define CHUNK  (KCODES / NWAVE)   // 256 codes per wave
#define TW     8            // codes per LDS e-tile
#define NTILE  (CHUNK / TW) // 32 tiles per wave

// ---------------- e_sq precompute: replicate np.sum(e*e, axis=1) pairwise-8 ----------------
__global__ void __launch_bounds__(256) esq_kernel(const float* __restrict__ e,
                                                  float* __restrict__ esq) {
    int k = blockIdx.x * 256 + threadIdx.x;
    if (k >= KCODES) return;
    {
#pragma clang fp contract(off)
        const float* row = e + k * DDIM;
        float r[8];
#pragma unroll
        for (int j = 0; j < 8; ++j) r[j] = row[j] * row[j];
#pragma unroll
        for (int i = 1; i < 8; ++i) {
#pragma unroll
            for (int j = 0; j < 8; ++j) {
                float v = row[i * 8 + j];
                r[j] += v * v;
            }
        }
        esq[k] = ((r[0] + r[1]) + (r[2] + r[3])) + ((r[4] + r[5]) + (r[6] + r[7]));
    }
}

// ---------------- main distance + argmin kernel (all-LDS) ----------------
// Block = 256 threads = 4 waves; 64 pixels/block (lane l = pixel blk*64+l).
// Wave w owns codes [w*256, w*256+256) as 32 double-buffered 8-code tiles.
__global__ void __launch_bounds__(256) argmin_kernel(const float* __restrict__ x,
                                                     const float* __restrict__ e,
                                                     const float* __restrict__ esq,
                                                     int* __restrict__ idx_out,
                                                     float* __restrict__ out) {
    __shared__ float x_lds[DDIM][64];            // 16KB [d][px]; read addr l*4 + imm -> 2-way banks
    __shared__ float e_lds[NWAVE][2][TW * DDIM]; // 16KB: per-wave dbuf 2KB tiles
    __shared__ float esq_lds[KCODES];            // 4KB
    __shared__ float sbest[NWAVE][64];
    __shared__ int   sidx[NWAVE][64];

    const int w = __builtin_amdgcn_readfirstlane(threadIdx.x >> 6);
    const int l = threadIdx.x & 63;
    const int pix = blockIdx.x * 64 + l;
    const int b = (blockIdx.x * 64) >> 10;       // same b for whole block (64-aligned)
    const int p0 = (blockIdx.x * 64) & 1023;

    // stage x tile (coalesced 256B rows) + esq
    {
        const float* xg = x + (size_t)b * 65536 + p0;
        for (int t = threadIdx.x; t < DDIM * 64; t += 256)
            x_lds[t >> 6][t & 63] = xg[(size_t)(t >> 6) * 1024 + (t & 63)];
        for (int t = threadIdx.x; t < KCODES; t += 256)
            esq_lds[t] = esq[t];
    }
    __syncthreads();

    // x_sq: EXACT numpy pairwise-8 (rounded products, no contraction), from LDS
    float xsq;
    {
#pragma clang fp contract(off)
        float r[8];
#pragma unroll
        for (int j = 0; j < 8; ++j) { float v = x_lds[j][l]; r[j] = v * v; }
#pragma unroll
        for (int ii = 1; ii < 8; ++ii) {
#pragma unroll
            for (int j = 0; j < 8; ++j) { float v = x_lds[ii * 8 + j][l]; r[j] += v * v; }
        }
        xsq = ((r[0] + r[1]) + (r[2] + r[3])) + ((r[4] + r[5]) + (r[6] + r[7]));
    }

    const int kbeg = w * CHUNK;                  // uniform (SGPR)

    // e staging: tile = 8 codes x 64 d = 2KB = 512 floats; lane l covers
    // floats [4l,4l+4) and [256+4l, 256+4l+4) -> two coalesced float4 loads.
    float4 st0, st1;
    auto LD = [&](int t) {
        const float* gp = e + (size_t)(kbeg + t * TW) * DDIM;
        st0 = *(const float4*)(gp + 4 * l);
        st1 = *(const float4*)(gp + 256 + 4 * l);
    };
    auto ST = [&](int par) {
        *(float4*)&e_lds[w][par][4 * l] = st0;
        *(float4*)&e_lds[w][par][256 + 4 * l] = st1;
    };

    LD(0); ST(0);        // tile 0 staged (compiler inserts vmcnt before ds_write)
    LD(1);               // tile 1 in flight; LDS-written after compute(0)

    float best = 3.4e38f;
    int bidx = 0;

#pragma unroll 1
    for (int t = 0; t < NTILE; ++t) {
        const int k = kbeg + t * TW;
        const float* eb = &e_lds[w][t & 1][0];

        float a[TW];
#pragma unroll
        for (int c = 0; c < TW; ++c) a[c] = 0.f;
        // d-quads ascending; per code the FMA chain is exactly d-ascending (d = 4q+j).
        // x: per-lane ds_read_b32 (2-way banks, free). e: uniform ds_read_b128
        // broadcast (same addr all lanes, imm offset) — conflict-free.
#pragma unroll
        for (int q = 0; q < 16; ++q) {
            const float x0 = x_lds[4 * q + 0][l];
            const float x1 = x_lds[4 * q + 1][l];
            const float x2 = x_lds[4 * q + 2][l];
            const float x3 = x_lds[4 * q + 3][l];
#pragma unroll
            for (int c = 0; c < TW; ++c) {
                const float4 ev = *(const float4*)&eb[c * 64 + 4 * q];
                a[c] = __builtin_fmaf(x0, ev.x, a[c]);
                a[c] = __builtin_fmaf(x1, ev.y, a[c]);
                a[c] = __builtin_fmaf(x2, ev.z, a[c]);
                a[c] = __builtin_fmaf(x3, ev.w, a[c]);
            }
        }

        // dist = (x_sq - 2*dot) + e_sq; strict < , ascending k
#pragma unroll
        for (int c = 0; c < TW; ++c) {
            const float s = (xsq - 2.0f * a[c]) + esq_lds[k + c];
            if (s < best) { best = s; bidx = k + c; }
        }

        // T14 tail: LDS-write prefetched tile (vmcnt wait lands after compute),
        // then issue the next global load.
        if (t + 1 < NTILE) {
            ST((t + 1) & 1);
            if (t + 2 < NTILE) LD(t + 2);
        }
    }

    // merge the 4 wave-chunks: ascending wave + strict '<' == global first-min
    sbest[w][l] = best;
    sidx[w][l] = bidx;
    __syncthreads();
    if (threadIdx.x < 64) {
        float bb = sbest[0][l];
        int bi = sidx[0][l];
#pragma unroll
        for (int c = 1; c < NWAVE; ++c) {
            float v = sbest[c][l];
            if (v < bb) { bb = v; bi = sidx[c][l]; }
        }
        idx_out[pix] = bi;
        out[IDX_OFF + pix] = (float)bi;   // harness reads d_out as float32
    }
}

// ---------------- gather + transpose + per-block loss partials ----------------
// block = one (b,d) plane of 1024 pixels; coalesced read/write.
__global__ void __launch_bounds__(256) gather_kernel(const float* __restrict__ x,
                                                     const float* __restrict__ e,
                                                     const int* __restrict__ idx,
                                                     float* __restrict__ out,
                                                     float* __restrict__ partial) {
    const int bd = blockIdx.x;          // = b*64 + d
    const int b = bd >> 6;
    const int d = bd & 63;
    const size_t base = (size_t)bd * 1024;
    const int* idxb = idx + b * 1024;

    float acc = 0.f;
#pragma unroll
    for (int j = 0; j < 4; ++j) {
        int p = threadIdx.x + j * 256;
        int k = idxb[p];
        float ev = e[k * 64 + d];
        float xv = x[base + p];
        out[1 + base + p] = ev;         // quantized (straight-through == codebook value)
        float df = ev - xv;
        acc = __builtin_fmaf(df, df, acc);
    }
    __shared__ float sm[256];
    sm[threadIdx.x] = acc;
    __syncthreads();
    for (int s = 128; s > 0; s >>= 1) {
        if (threadIdx.x < s) sm[threadIdx.x] += sm[threadIdx.x + s];
        __syncthreads();
    }
    if (threadIdx.x == 0) partial[bd] = sm[0];
}

// ---------------- deterministic loss finalize ----------------
__global__ void __launch_bounds__(256) loss_kernel(const float* __restrict__ partial,
                                                   float* __restrict__ out) {
    float acc = 0.f;
    for (int i = threadIdx.x; i < 4096; i += 256) acc += partial[i];
    __shared__ float sm[256];
    sm[threadIdx.x] = acc;
    __syncthreads();
    for (int s = 128; s > 0; s >>= 1) {
        if (threadIdx.x < s) sm[threadIdx.x] += sm[threadIdx.x + s];
        __syncthreads();
    }
    // loss = q_latent + 0.25*e_latent = 1.25 * mean(diff^2)
    if (threadIdx.x == 0) out[0] = sm[0] * (1.25f / 4194304.f);
}

extern "C" void kernel_launch(void* const* d_in, const int* in_sizes, int n_in,
                              void* d_out, int out_size, void* d_ws, size_t ws_size,
                              hipStream_t stream) {
    const float* x = (const float*)d_in[0];   // [64,64,32,32]
    const float* e = (const float*)d_in[1];   // [1024,64]
    float* out = (float*)d_out;

    // ws: [0,4KB) e_sq | [4KB, 4KB+256KB) idx int32 | then 16KB partials
    float* esq = (float*)d_ws;
    int* idx = (int*)((char*)d_ws + 4096);
    float* partial = (float*)((char*)d_ws + 4096 + NPIX * 4);

    esq_kernel<<<4, 256, 0, stream>>>(e, esq);
    argmin_kernel<<<NPIX / 64, 256, 0, stream>>>(x, e, esq, idx, out);
    gather_kernel<<<4096, 256, 0, stream>>>(x, e, idx, out, partial);
    loss_kernel<<<1, 256, 0, stream>>>(partial, out);
}

// Round 13
// 624.171 us; speedup vs baseline: 2.1625x; 2.1625x over previous
//
#include <hip/hip_runtime.h>

// VQ-VAE VectorQuantizer forward, fp32, MI355X.
// B=64, C=D=64, H=W=32 -> N=65536 pixels, K=1024 codes.
// Outputs (flat concat): [0] loss, [1..4194305) quantized BCHW, [4194305..) indices (as float)
//
// R13: MFMA pivot. scores via 3-term bf16-split GEMM on the matrix pipe
// (xh*eh + xh*el + xl*eh, fp32 acc), per-pixel top-2 approx tracking; if
// m2 > m1 + MARGIN (5e-4 >> 2*eps~2e-5), approx winner == reference argmin
// provably. Rare flagged pixels (~1e-3 fraction) get a full 1024-code exact
// recompute with the BIT-EXACT reference arithmetic (same as R0-R12, passed
// at absmax 3.8e-6): pairwise-8 x_sq (contract off), d-ascending fp32 FMA
// chain, (xsq-2d)+esq, ascending-k strict-<.
// MFMA facts used: C/D layout col=lane&15,row=(lane>>4)*4+reg (HW-verified);
// A/B loaded with the SAME (lane,j)->k map so any k-pattern error cancels
// (sum over k is permutation-invariant; this path is approximate anyway).
// Anti-spill (R6/R7/R12 lessons): kt-loop unroll 1, named frags w/ constant
// indices, launch_bounds cap 128 vs ~70 demand, x-tile in LDS (R9-proven).

#define KCODES 1024
#define DDIM   64
#define NPIX   65536
#define QELEMS 4194304
#define IDX_OFF (1 + QELEMS)
#define MARGIN 5e-4f

typedef __attribute__((ext_vector_type(8))) short bf16x8;
typedef __attribute__((ext_vector_type(4))) float f32x4;

static __device__ __forceinline__ unsigned short f2bf(float f) {
    unsigned int u = __float_as_uint(f);
    unsigned int r = (u + 0x7FFFu + ((u >> 16) & 1u)) >> 16;   // RNE
    return (unsigned short)r;
}
static __device__ __forceinline__ float bf2f(unsigned short h) {
    return __uint_as_float(((unsigned int)h) << 16);
}

// ---------------- e prep: esq (EXACT numpy pairwise-8) + bf16 split ----------------
__global__ void __launch_bounds__(256) esplit_kernel(const float* __restrict__ e,
                                                     float* __restrict__ esq,
                                                     unsigned short* __restrict__ Eh,
                                                     unsigned short* __restrict__ El) {
    int k = blockIdx.x * 256 + threadIdx.x;
    if (k >= KCODES) return;
    const float* row = e + k * DDIM;
    {
#pragma clang fp contract(off)
        float r[8];
#pragma unroll
        for (int j = 0; j < 8; ++j) r[j] = row[j] * row[j];
#pragma unroll
        for (int i = 1; i < 8; ++i) {
#pragma unroll
            for (int j = 0; j < 8; ++j) { float v = row[i * 8 + j]; r[j] += v * v; }
        }
        esq[k] = ((r[0] + r[1]) + (r[2] + r[3])) + ((r[4] + r[5]) + (r[6] + r[7]));
    }
#pragma unroll
    for (int d = 0; d < DDIM; ++d) {
        float v = row[d];
        unsigned short h = f2bf(v);
        Eh[k * DDIM + d] = h;
        El[k * DDIM + d] = f2bf(v - bf2f(h));
    }
}

// ---------------- MFMA approx scores + top-2 argmin ----------------
// Block = 256 thr = 4 waves; 64 px/block (wave w: px w*16..w*16+15).
// Per kt (16 codes): 6 mfma (3 split-terms x 2 d-halves), epilogue top-2.
__global__ void __launch_bounds__(256, 4) gemm_kernel(const float* __restrict__ x,
                                                      const unsigned short* __restrict__ Eh,
                                                      const unsigned short* __restrict__ El,
                                                      const float* __restrict__ esq,
                                                      int* __restrict__ flag,
                                                      int* __restrict__ idx,
                                                      float* __restrict__ out) {
    __shared__ float x_lds[DDIM][64];   // 16KB [d][px_local]
    __shared__ float esq_lds[KCODES];   // 4KB

    const int tid = threadIdx.x;
    const int w = __builtin_amdgcn_readfirstlane(tid >> 6);
    const int l = tid & 63;
    const int g = l >> 4;              // 0..3
    const int col = l & 15;            // k-within-tile AND A-row(px) slot
    const int pxbase = blockIdx.x * 64;
    const int b = pxbase >> 10;
    const int p0 = pxbase & 1023;

    // stage x tile (coalesced 256B rows) + esq
    {
        const float* xg = x + (size_t)b * 65536 + p0;
        for (int t = tid; t < DDIM * 64; t += 256)
            x_lds[t >> 6][t & 63] = xg[(size_t)(t >> 6) * 1024 + (t & 63)];
        for (int t = tid; t < KCODES; t += 256)
            esq_lds[t] = esq[t];
    }
    __syncthreads();

    // A fragments: row = col (px_local = w*16+col), k(d)-slot = g*8 + j (+32 per d-half)
    bf16x8 Ah0, Ah1, Al0, Al1;
    {
        const int pxl = w * 16 + col;
#pragma unroll
        for (int j = 0; j < 8; ++j) {
            float v0 = x_lds[g * 8 + j][pxl];
            unsigned short h0 = f2bf(v0);
            Ah0[j] = (short)h0;
            Al0[j] = (short)f2bf(v0 - bf2f(h0));
            float v1 = x_lds[32 + g * 8 + j][pxl];
            unsigned short h1 = f2bf(v1);
            Ah1[j] = (short)h1;
            Al1[j] = (short)f2bf(v1 - bf2f(h1));
        }
    }

    float m1_0 = 3.4e38f, m1_1 = 3.4e38f, m1_2 = 3.4e38f, m1_3 = 3.4e38f;
    float m2_0 = 3.4e38f, m2_1 = 3.4e38f, m2_2 = 3.4e38f, m2_3 = 3.4e38f;
    int i1_0 = 0, i1_1 = 0, i1_2 = 0, i1_3 = 0;

#pragma unroll 1
    for (int kt = 0; kt < KCODES / 16; ++kt) {
        const int kc = kt * 16 + col;                 // lane's code column
        const unsigned short* ehp = Eh + kc * DDIM + g * 8;
        const unsigned short* elp = El + kc * DDIM + g * 8;
        const bf16x8 Bh0 = *(const bf16x8*)(ehp);
        const bf16x8 Bh1 = *(const bf16x8*)(ehp + 32);
        const bf16x8 Bl0 = *(const bf16x8*)(elp);
        const bf16x8 Bl1 = *(const bf16x8*)(elp + 32);

        f32x4 acc = {0.f, 0.f, 0.f, 0.f};
        acc = __builtin_amdgcn_mfma_f32_16x16x32_bf16(Ah0, Bh0, acc, 0, 0, 0);
        acc = __builtin_amdgcn_mfma_f32_16x16x32_bf16(Ah1, Bh1, acc, 0, 0, 0);
        acc = __builtin_amdgcn_mfma_f32_16x16x32_bf16(Ah0, Bl0, acc, 0, 0, 0);
        acc = __builtin_amdgcn_mfma_f32_16x16x32_bf16(Ah1, Bl1, acc, 0, 0, 0);
        acc = __builtin_amdgcn_mfma_f32_16x16x32_bf16(Al0, Bh0, acc, 0, 0, 0);
        acc = __builtin_amdgcn_mfma_f32_16x16x32_bf16(Al1, Bh1, acc, 0, 0, 0);

        const float qe = esq_lds[kt * 16 + col];
        // lane's acc[r] = score tile element (row=g*4+r, col) -> px w*16+g*4+r, code kc
#define TOP2(S, M1, M2, I1)                                   \
        {                                                     \
            float s_ = __builtin_fmaf(-2.0f, (S), qe);        \
            float t_ = fmaxf(s_, M1);                         \
            M2 = fminf(M2, t_);                               \
            if (s_ < M1) I1 = kc;                             \
            M1 = fminf(M1, s_);                               \
        }
        TOP2(acc[0], m1_0, m2_0, i1_0)
        TOP2(acc[1], m1_1, m2_1, i1_1)
        TOP2(acc[2], m1_2, m2_2, i1_2)
        TOP2(acc[3], m1_3, m2_3, i1_3)
#undef TOP2
    }

    // cross-lane merge over the 16 lanes of group g (same px rows)
#define MERGE(M1, M2, I1, R)                                                   \
    {                                                                          \
        float a1 = M1, a2 = M2; int j1 = I1;                                   \
        _Pragma("unroll")                                                      \
        for (int off = 1; off < 16; off <<= 1) {                               \
            float b1 = __shfl_xor(a1, off);                                    \
            int jb = __shfl_xor(j1, off);                                      \
            float b2 = __shfl_xor(a2, off);                                    \
            float hi = fmaxf(a1, b1);                                          \
            a2 = fminf(fminf(a2, b2), hi);                                     \
            if (b1 < a1) j1 = jb;                                              \
            a1 = fminf(a1, b1);                                                \
        }                                                                      \
        if (col == 0) {                                                        \
            int px = pxbase + w * 16 + g * 4 + (R);                            \
            flag[px] = (a2 <= a1 + MARGIN) ? 1 : 0;                            \
            idx[px] = j1;                                                      \
            out[IDX_OFF + px] = (float)j1;                                     \
        }                                                                      \
    }
    MERGE(m1_0, m2_0, i1_0, 0)
    MERGE(m1_1, m2_1, i1_1, 1)
    MERGE(m1_2, m2_2, i1_2, 2)
    MERGE(m1_3, m2_3, i1_3, 3)
#undef MERGE
}

// ---------------- cleanup: exact reference argmin for flagged pixels ----------------
// 1 wave per block (block=64) so __syncthreads is wave-local and safe in the
// (wave-uniform) flagged-pixel loop.
__global__ void __launch_bounds__(64) cleanup_kernel(const float* __restrict__ x,
                                                     const float* __restrict__ e,
                                                     const float* __restrict__ esq,
                                                     const int* __restrict__ flag,
                                                     int* __restrict__ idx,
                                                     float* __restrict__ out) {
    __shared__ float xs[DDIM];
    const int l = threadIdx.x;
    const int base = blockIdx.x * 64;
    unsigned long long mask = __ballot(flag[base + l] != 0);

    while (mask) {
        const int bit = __ffsll((long long)mask) - 1;
        mask &= mask - 1;
        const int p = base + bit;
        const int bb = p >> 10;
        const int pp = p & 1023;
        xs[l] = x[(size_t)bb * 65536 + (size_t)l * 1024 + pp];
        __syncthreads();

        // xsq: EXACT numpy pairwise-8
        float xsq;
        {
#pragma clang fp contract(off)
            float r[8];
#pragma unroll
            for (int j = 0; j < 8; ++j) { float v = xs[j]; r[j] = v * v; }
#pragma unroll
            for (int ii = 1; ii < 8; ++ii) {
#pragma unroll
                for (int j = 0; j < 8; ++j) { float v = xs[ii * 8 + j]; r[j] += v * v; }
            }
            xsq = ((r[0] + r[1]) + (r[2] + r[3])) + ((r[4] + r[5]) + (r[6] + r[7]));
        }

        // lane l: codes [l*16, l*16+16) ascending; exact reference chain per code
        float best = 3.4e38f;
        int bi = 0;
#pragma unroll 1
        for (int c = 0; c < 16; ++c) {
            const int k = l * 16 + c;
            const float* er = e + (size_t)k * DDIM;
            float dt = 0.f;
#pragma unroll
            for (int d = 0; d < DDIM; ++d) dt = __builtin_fmaf(xs[d], er[d], dt);
            const float s = (xsq - 2.0f * dt) + esq[k];
            if (s < best) { best = s; bi = k; }
        }
        // cross-lane: lowest value, ties -> lowest k (== first occurrence)
#pragma unroll
        for (int off = 1; off < 64; off <<= 1) {
            float b2 = __shfl_xor(best, off);
            int k2 = __shfl_xor(bi, off);
            if (b2 < best || (b2 == best && k2 < bi)) { best = b2; bi = k2; }
        }
        if (l == 0) { idx[p] = bi; out[IDX_OFF + p] = (float)bi; }
        __syncthreads();
    }
}

// ---------------- gather + transpose + per-block loss partials ----------------
__global__ void __launch_bounds__(256) gather_kernel(const float* __restrict__ x,
                                                     const float* __restrict__ e,
                                                     const int* __restrict__ idx,
                                                     float* __restrict__ out,
                                                     float* __restrict__ partial) {
    const int bd = blockIdx.x;          // = b*64 + d
    const int b = bd >> 6;
    const int d = bd & 63;
    const size_t base = (size_t)bd * 1024;
    const int* idxb = idx + b * 1024;

    float acc = 0.f;
#pragma unroll
    for (int j = 0; j < 4; ++j) {
        int p = threadIdx.x + j * 256;
        int k = idxb[p];
        float ev = e[k * 64 + d];
        float xv = x[base + p];
        out[1 + base + p] = ev;
        float df = ev - xv;
        acc = __builtin_fmaf(df, df, acc);
    }
    __shared__ float sm[256];
    sm[threadIdx.x] = acc;
    __syncthreads();
    for (int s = 128; s > 0; s >>= 1) {
        if (threadIdx.x < s) sm[threadIdx.x] += sm[threadIdx.x + s];
        __syncthreads();
    }
    if (threadIdx.x == 0) partial[bd] = sm[0];
}

__global__ void __launch_bounds__(256) loss_kernel(const float* __restrict__ partial,
                                                   float* __restrict__ out) {
    float acc = 0.f;
    for (int i = threadIdx.x; i < 4096; i += 256) acc += partial[i];
    __shared__ float sm[256];
    sm[threadIdx.x] = acc;
    __syncthreads();
    for (int s = 128; s > 0; s >>= 1) {
        if (threadIdx.x < s) sm[threadIdx.x] += sm[threadIdx.x + s];
        __syncthreads();
    }
    if (threadIdx.x == 0) out[0] = sm[0] * (1.25f / 4194304.f);
}

extern "C" void kernel_launch(void* const* d_in, const int* in_sizes, int n_in,
                              void* d_out, int out_size, void* d_ws, size_t ws_size,
                              hipStream_t stream) {
    const float* x = (const float*)d_in[0];   // [64,64,32,32]
    const float* e = (const float*)d_in[1];   // [1024,64]
    float* out = (float*)d_out;

    // ws: esq 4KB | Eh 128KB | El 128KB | flag 256KB | idx 256KB | partial 16KB
    char* wsb = (char*)d_ws;
    float*          esq     = (float*)wsb;
    unsigned short* Eh      = (unsigned short*)(wsb + 4096);
    unsigned short* El      = (unsigned short*)(wsb + 4096 + 131072);
    int*            flag    = (int*)(wsb + 4096 + 2 * 131072);
    int*            idx     = (int*)(wsb + 4096 + 2 * 131072 + NPIX * 4);
    float*          partial = (float*)(wsb + 4096 + 2 * 131072 + 2 * NPIX * 4);

    esplit_kernel<<<4, 256, 0, stream>>>(e, esq, Eh, El);
    gemm_kernel<<<NPIX / 64, 256, 0, stream>>>(x, Eh, El, esq, flag, idx, out);
    cleanup_kernel<<<NPIX / 64, 64, 0, stream>>>(x, e, esq, flag, idx, out);
    gather_kernel<<<4096, 256, 0, stream>>>(x, e, idx, out, partial);
    loss_kernel<<<1, 256, 0, stream>>>(partial, out);
}

// Round 14
// 227.014 us; speedup vs baseline: 5.9457x; 2.7495x over previous
//
#include <hip/hip_runtime.h>

// VQ-VAE VectorQuantizer forward, fp32, MI355X.
// B=64, C=D=64, H=W=32 -> N=65536 pixels, K=1024 codes.
// Outputs (flat concat): [0] loss, [1..4194305) quantized BCHW, [4194305..) indices (as float)
//
// R14: R13 MFMA structure with (a) MARGIN 5e-4 -> 8e-5 (R13 flagged ~20% of
// pixels: undivided top-2 gap ~2.4e-3, margin was in the wrong units; audited
// approx-vs-ref deviation <= 1.2e-5 per score -> 2.4e-5 decision-safe, 8e-5 =
// 3.3x safety), (b) block-cooperative cleanup (256 thr, 4 codes/thread, exact
// reference chains, lexicographic (s,k) reduce) replacing the 36us/pixel
// serial wave version, (c) software-pipelined B prefetch in gemm (two named
// frag sets; loads for tile t+1 issued before compute of t).
// Exact-path arithmetic BIT-IDENTICAL to R0-R13 (passed, absmax 3.8e-6):
// pairwise-8 x_sq (contract off), d-ascending fp32 FMA chain,
// (xsq-2d)+esq, ascending-k strict-<.

#define KCODES 1024
#define DDIM   64
#define NPIX   65536
#define QELEMS 4194304
#define IDX_OFF (1 + QELEMS)
#define MARGIN 8e-5f

typedef __attribute__((ext_vector_type(8))) short bf16x8;
typedef __attribute__((ext_vector_type(4))) float f32x4;

static __device__ __forceinline__ unsigned short f2bf(float f) {
    unsigned int u = __float_as_uint(f);
    unsigned int r = (u + 0x7FFFu + ((u >> 16) & 1u)) >> 16;   // RNE
    return (unsigned short)r;
}
static __device__ __forceinline__ float bf2f(unsigned short h) {
    return __uint_as_float(((unsigned int)h) << 16);
}

// ---------------- e prep: esq (EXACT numpy pairwise-8) + bf16 split ----------------
__global__ void __launch_bounds__(256) esplit_kernel(const float* __restrict__ e,
                                                     float* __restrict__ esq,
                                                     unsigned short* __restrict__ Eh,
                                                     unsigned short* __restrict__ El) {
    int k = blockIdx.x * 256 + threadIdx.x;
    if (k >= KCODES) return;
    const float* row = e + k * DDIM;
    {
#pragma clang fp contract(off)
        float r[8];
#pragma unroll
        for (int j = 0; j < 8; ++j) r[j] = row[j] * row[j];
#pragma unroll
        for (int i = 1; i < 8; ++i) {
#pragma unroll
            for (int j = 0; j < 8; ++j) { float v = row[i * 8 + j]; r[j] += v * v; }
        }
        esq[k] = ((r[0] + r[1]) + (r[2] + r[3])) + ((r[4] + r[5]) + (r[6] + r[7]));
    }
#pragma unroll
    for (int d = 0; d < DDIM; ++d) {
        float v = row[d];
        unsigned short h = f2bf(v);
        Eh[k * DDIM + d] = h;
        El[k * DDIM + d] = f2bf(v - bf2f(h));
    }
}

// ---------------- MFMA approx scores + top-2 argmin (B-prefetch pipelined) ----------------
// Block = 256 thr = 4 waves; 64 px/block (wave w: px w*16..w*16+15).
__global__ void __launch_bounds__(256, 4) gemm_kernel(const float* __restrict__ x,
                                                      const unsigned short* __restrict__ Eh,
                                                      const unsigned short* __restrict__ El,
                                                      const float* __restrict__ esq,
                                                      int* __restrict__ flag,
                                                      int* __restrict__ idx,
                                                      float* __restrict__ out) {
    __shared__ float x_lds[DDIM][64];   // 16KB [d][px_local]
    __shared__ float esq_lds[KCODES];   // 4KB

    const int tid = threadIdx.x;
    const int w = __builtin_amdgcn_readfirstlane(tid >> 6);
    const int l = tid & 63;
    const int g = l >> 4;              // 0..3
    const int col = l & 15;
    const int pxbase = blockIdx.x * 64;
    const int b = pxbase >> 10;
    const int p0 = pxbase & 1023;

    {
        const float* xg = x + (size_t)b * 65536 + p0;
        for (int t = tid; t < DDIM * 64; t += 256)
            x_lds[t >> 6][t & 63] = xg[(size_t)(t >> 6) * 1024 + (t & 63)];
        for (int t = tid; t < KCODES; t += 256)
            esq_lds[t] = esq[t];
    }
    __syncthreads();

    // A fragments: row = col (px_local = w*16+col), k(d)-slot = g*8 + j (+32 per d-half)
    bf16x8 Ah0, Ah1, Al0, Al1;
    {
        const int pxl = w * 16 + col;
#pragma unroll
        for (int j = 0; j < 8; ++j) {
            float v0 = x_lds[g * 8 + j][pxl];
            unsigned short h0 = f2bf(v0);
            Ah0[j] = (short)h0;
            Al0[j] = (short)f2bf(v0 - bf2f(h0));
            float v1 = x_lds[32 + g * 8 + j][pxl];
            unsigned short h1 = f2bf(v1);
            Ah1[j] = (short)h1;
            Al1[j] = (short)f2bf(v1 - bf2f(h1));
        }
    }

    float m1_0 = 3.4e38f, m1_1 = 3.4e38f, m1_2 = 3.4e38f, m1_3 = 3.4e38f;
    float m2_0 = 3.4e38f, m2_1 = 3.4e38f, m2_2 = 3.4e38f, m2_3 = 3.4e38f;
    int i1_0 = 0, i1_1 = 0, i1_2 = 0, i1_3 = 0;

    const size_t lbase = (size_t)col * DDIM + g * 8;   // lane's row offset within a 16-code tile

    bf16x8 Xh0, Xh1, Xl0, Xl1;   // set A
    bf16x8 Yh0, Yh1, Yl0, Yl1;   // set B

#define LDB(KT, H0, H1, L0, L1)                                               \
    {                                                                         \
        const unsigned short* ehp = Eh + (size_t)(KT) * 16 * DDIM + lbase;    \
        const unsigned short* elp = El + (size_t)(KT) * 16 * DDIM + lbase;    \
        H0 = *(const bf16x8*)(ehp);                                           \
        H1 = *(const bf16x8*)(ehp + 32);                                      \
        L0 = *(const bf16x8*)(elp);                                           \
        L1 = *(const bf16x8*)(elp + 32);                                      \
    }

#define COMPUTE(KT, H0, H1, L0, L1)                                           \
    {                                                                         \
        f32x4 acc = {0.f, 0.f, 0.f, 0.f};                                     \
        acc = __builtin_amdgcn_mfma_f32_16x16x32_bf16(Ah0, H0, acc, 0, 0, 0); \
        acc = __builtin_amdgcn_mfma_f32_16x16x32_bf16(Ah1, H1, acc, 0, 0, 0); \
        acc = __builtin_amdgcn_mfma_f32_16x16x32_bf16(Ah0, L0, acc, 0, 0, 0); \
        acc = __builtin_amdgcn_mfma_f32_16x16x32_bf16(Ah1, L1, acc, 0, 0, 0); \
        acc = __builtin_amdgcn_mfma_f32_16x16x32_bf16(Al0, H0, acc, 0, 0, 0); \
        acc = __builtin_amdgcn_mfma_f32_16x16x32_bf16(Al1, H1, acc, 0, 0, 0); \
        const int kc = (KT) * 16 + col;                                       \
        const float qe = esq_lds[(KT) * 16 + col];                            \
        {                                                                     \
            float s_ = __builtin_fmaf(-2.0f, acc[0], qe);                     \
            float t_ = fmaxf(s_, m1_0);                                       \
            m2_0 = fminf(m2_0, t_);                                           \
            if (s_ < m1_0) i1_0 = kc;                                         \
            m1_0 = fminf(m1_0, s_);                                           \
        }                                                                     \
        {                                                                     \
            float s_ = __builtin_fmaf(-2.0f, acc[1], qe);                     \
            float t_ = fmaxf(s_, m1_1);                                       \
            m2_1 = fminf(m2_1, t_);                                           \
            if (s_ < m1_1) i1_1 = kc;                                         \
            m1_1 = fminf(m1_1, s_);                                           \
        }                                                                     \
        {                                                                     \
            float s_ = __builtin_fmaf(-2.0f, acc[2], qe);                     \
            float t_ = fmaxf(s_, m1_2);                                       \
            m2_2 = fminf(m2_2, t_);                                           \
            if (s_ < m1_2) i1_2 = kc;                                         \
            m1_2 = fminf(m1_2, s_);                                           \
        }                                                                     \
        {                                                                     \
            float s_ = __builtin_fmaf(-2.0f, acc[3], qe);                     \
            float t_ = fmaxf(s_, m1_3);                                       \
            m2_3 = fminf(m2_3, t_);                                           \
            if (s_ < m1_3) i1_3 = kc;                                         \
            m1_3 = fminf(m1_3, s_);                                           \
        }                                                                     \
    }

    // software pipeline: loads for tile t+1 in flight during compute of tile t
    LDB(0, Xh0, Xh1, Xl0, Xl1)
#pragma unroll 1
    for (int t = 0; t < 32; ++t) {
        LDB(2 * t + 1, Yh0, Yh1, Yl0, Yl1)
        COMPUTE(2 * t, Xh0, Xh1, Xl0, Xl1)
        if (t < 31) LDB(2 * t + 2, Xh0, Xh1, Xl0, Xl1)
        COMPUTE(2 * t + 1, Yh0, Yh1, Yl0, Yl1)
    }
#undef LDB
#undef COMPUTE

    // cross-lane merge over the 16 lanes of group g (same px rows)
#define MERGE(M1, M2, I1, R)                                                   \
    {                                                                          \
        float a1 = M1, a2 = M2; int j1 = I1;                                   \
        _Pragma("unroll")                                                      \
        for (int off = 1; off < 16; off <<= 1) {                               \
            float b1 = __shfl_xor(a1, off);                                    \
            int jb = __shfl_xor(j1, off);                                      \
            float b2 = __shfl_xor(a2, off);                                    \
            float hi = fmaxf(a1, b1);                                          \
            a2 = fminf(fminf(a2, b2), hi);                                     \
            if (b1 < a1) j1 = jb;                                              \
            a1 = fminf(a1, b1);                                                \
        }                                                                      \
        if (col == 0) {                                                        \
            int px = pxbase + w * 16 + g * 4 + (R);                            \
            flag[px] = (a2 <= a1 + MARGIN) ? 1 : 0;                            \
            idx[px] = j1;                                                      \
            out[IDX_OFF + px] = (float)j1;                                     \
        }                                                                      \
    }
    MERGE(m1_0, m2_0, i1_0, 0)
    MERGE(m1_1, m2_1, i1_1, 1)
    MERGE(m1_2, m2_2, i1_2, 2)
    MERGE(m1_3, m2_3, i1_3, 3)
#undef MERGE
}

// ---------------- cleanup: exact reference argmin, block-cooperative ----------------
// 256 blocks x 256 thr; block covers 256 pixels; per flagged pixel the whole
// block works: thread t owns codes [4t, 4t+4) (ascending), exact d-ascending
// fp32 chains; reduce lexicographic (s,k) == first-occurrence argmin.
__global__ void __launch_bounds__(256) cleanup_kernel(const float* __restrict__ x,
                                                      const float* __restrict__ e,
                                                      const float* __restrict__ esq,
                                                      const int* __restrict__ flag,
                                                      int* __restrict__ idx,
                                                      float* __restrict__ out) {
    __shared__ float xs[DDIM];
    __shared__ unsigned long long wmask[4];
    __shared__ float rbest[4];
    __shared__ int   ridx[4];

    const int tid = threadIdx.x;
    const int base = blockIdx.x * 256;

    unsigned long long m = __ballot(flag[base + tid] != 0);
    if ((tid & 63) == 0) wmask[tid >> 6] = m;
    __syncthreads();

#pragma unroll 1
    for (int seg = 0; seg < 4; ++seg) {
        unsigned long long mask = wmask[seg];   // uniform across block
        while (mask) {
            const int bit = __ffsll((long long)mask) - 1;
            mask &= mask - 1;
            const int p = base + seg * 64 + bit;

            if (tid < 64)
                xs[tid] = x[(size_t)(p >> 10) * 65536 + (size_t)tid * 1024 + (p & 1023)];
            __syncthreads();

            // xsq: EXACT numpy pairwise-8 (broadcast LDS reads)
            float xsq;
            {
#pragma clang fp contract(off)
                float r[8];
#pragma unroll
                for (int j = 0; j < 8; ++j) { float v = xs[j]; r[j] = v * v; }
#pragma unroll
                for (int ii = 1; ii < 8; ++ii) {
#pragma unroll
                    for (int j = 0; j < 8; ++j) { float v = xs[ii * 8 + j]; r[j] += v * v; }
                }
                xsq = ((r[0] + r[1]) + (r[2] + r[3])) + ((r[4] + r[5]) + (r[6] + r[7]));
            }

            // thread t: codes 4t..4t+3, exact reference chain per code
            float best = 3.4e38f;
            int bi = 0;
#pragma unroll
            for (int c = 0; c < 4; ++c) {
                const int k = tid * 4 + c;
                const float* er = e + (size_t)k * DDIM;
                float dt = 0.f;
#pragma unroll
                for (int d = 0; d < DDIM; ++d) dt = __builtin_fmaf(xs[d], er[d], dt);
                const float s = (xsq - 2.0f * dt) + esq[k];
                if (s < best) { best = s; bi = k; }
            }
            // wave reduce lexicographic (s,k): lowest s, ties -> lowest k
#pragma unroll
            for (int off = 1; off < 64; off <<= 1) {
                float b2 = __shfl_xor(best, off);
                int k2 = __shfl_xor(bi, off);
                if (b2 < best || (b2 == best && k2 < bi)) { best = b2; bi = k2; }
            }
            if ((tid & 63) == 0) { rbest[tid >> 6] = best; ridx[tid >> 6] = bi; }
            __syncthreads();
            if (tid == 0) {
                float bb = rbest[0]; int bj = ridx[0];
#pragma unroll
                for (int c2 = 1; c2 < 4; ++c2) {
                    if (rbest[c2] < bb || (rbest[c2] == bb && ridx[c2] < bj)) {
                        bb = rbest[c2]; bj = ridx[c2];
                    }
                }
                idx[p] = bj;
                out[IDX_OFF + p] = (float)bj;
            }
            __syncthreads();
        }
    }
}

// ---------------- gather + transpose + per-block loss partials ----------------
__global__ void __launch_bounds__(256) gather_kernel(const float* __restrict__ x,
                                                     const float* __restrict__ e,
                                                     const int* __restrict__ idx,
                                                     float* __restrict__ out,
                                                     float* __restrict__ partial) {
    const int bd = blockIdx.x;          // = b*64 + d
    const int b = bd >> 6;
    const int d = bd & 63;
    const size_t base = (size_t)bd * 1024;
    const int* idxb = idx + b * 1024;

    float acc = 0.f;
#pragma unroll
    for (int j = 0; j < 4; ++j) {
        int p = threadIdx.x + j * 256;
        int k = idxb[p];
        float ev = e[k * 64 + d];
        float xv = x[base + p];
        out[1 + base + p] = ev;
        float df = ev - xv;
        acc = __builtin_fmaf(df, df, acc);
    }
    __shared__ float sm[256];
    sm[threadIdx.x] = acc;
    __syncthreads();
    for (int s = 128; s > 0; s >>= 1) {
        if (threadIdx.x < s) sm[threadIdx.x] += sm[threadIdx.x + s];
        __syncthreads();
    }
    if (threadIdx.x == 0) partial[bd] = sm[0];
}

__global__ void __launch_bounds__(256) loss_kernel(const float* __restrict__ partial,
                                                   float* __restrict__ out) {
    float acc = 0.f;
    for (int i = threadIdx.x; i < 4096; i += 256) acc += partial[i];
    __shared__ float sm[256];
    sm[threadIdx.x] = acc;
    __syncthreads();
    for (int s = 128; s > 0; s >>= 1) {
        if (threadIdx.x < s) sm[threadIdx.x] += sm[threadIdx.x + s];
        __syncthreads();
    }
    if (threadIdx.x == 0) out[0] = sm[0] * (1.25f / 4194304.f);
}

extern "C" void kernel_launch(void* const* d_in, const int* in_sizes, int n_in,
                              void* d_out, int out_size, void* d_ws, size_t ws_size,
                              hipStream_t stream) {
    const float* x = (const float*)d_in[0];   // [64,64,32,32]
    const float* e = (const float*)d_in[1];   // [1024,64]
    float* out = (float*)d_out;

    // ws: esq 4KB | Eh 128KB | El 128KB | flag 256KB | idx 256KB | partial 16KB
    char* wsb = (char*)d_ws;
    float*          esq     = (float*)wsb;
    unsigned short* Eh      = (unsigned short*)(wsb + 4096);
    unsigned short* El      = (unsigned short*)(wsb + 4096 + 131072);
    int*            flag    = (int*)(wsb + 4096 + 2 * 131072);
    int*            idx     = (int*)(wsb + 4096 + 2 * 131072 + NPIX * 4);
    float*          partial = (float*)(wsb + 4096 + 2 * 131072 + 2 * NPIX * 4);

    esplit_kernel<<<4, 256, 0, stream>>>(e, esq, Eh, El);
    gemm_kernel<<<NPIX / 64, 256, 0, stream>>>(x, Eh, El, esq, flag, idx, out);
    cleanup_kernel<<<NPIX / 256, 256, 0, stream>>>(x, e, esq, flag, idx, out);
    gather_kernel<<<4096, 256, 0, stream>>>(x, e, idx, out, partial);
    loss_kernel<<<1, 256, 0, stream>>>(partial, out);
}

// Round 15
// 147.921 us; speedup vs baseline: 9.1249x; 1.5347x over previous
//
#include <hip/hip_runtime.h>

// VQ-VAE VectorQuantizer forward, fp32, MI355X.
// B=64, C=D=64, H=W=32 -> N=65536 pixels, K=1024 codes.
// Outputs (flat concat): [0] loss, [1..4194305) quantized BCHW, [4194305..) indices (as float)
//
// R15: gemm restructured — B (Eh/El) staged per-tile in LDS, SHARED by all 4
// waves (R14: each wave privately re-read 256KB -> 1GB L2 traffic, 1-deep
// pipeline, 80% stall). XOR-swizzled tile (dbyte ^= (code&7)<<4 on write AND
// read) makes ds_read_b128 conflict-free. Pipeline per tile: ST(t+1) ->
// LD(t+2) -> compute(t) -> barrier (full-tile latency cover for the global
// load). MFMA split into 3 independent 2-chains (hh/hl/lh) + final sum.
// MARGIN 8e-5 (R14-validated); exact-path arithmetic BIT-IDENTICAL to R0-R14
// (passed, absmax 3.8e-6): pairwise-8 x_sq (contract off), d-ascending fp32
// FMA chain, (xsq-2d)+esq, ascending-k strict-<.

#define KCODES 1024
#define DDIM   64
#define NPIX   65536
#define QELEMS 4194304
#define IDX_OFF (1 + QELEMS)
#define MARGIN 8e-5f
#define NTILE  64          // 1024 codes / 16 per tile

typedef __attribute__((ext_vector_type(8))) short bf16x8;
typedef __attribute__((ext_vector_type(4))) float f32x4;

static __device__ __forceinline__ unsigned short f2bf(float f) {
    unsigned int u = __float_as_uint(f);
    unsigned int r = (u + 0x7FFFu + ((u >> 16) & 1u)) >> 16;   // RNE
    return (unsigned short)r;
}
static __device__ __forceinline__ float bf2f(unsigned short h) {
    return __uint_as_float(((unsigned int)h) << 16);
}

// ---------------- e prep: esq (EXACT numpy pairwise-8) + bf16 split ----------------
__global__ void __launch_bounds__(256) esplit_kernel(const float* __restrict__ e,
                                                     float* __restrict__ esq,
                                                     unsigned short* __restrict__ Eh,
                                                     unsigned short* __restrict__ El) {
    int k = blockIdx.x * 256 + threadIdx.x;
    if (k >= KCODES) return;
    const float* row = e + k * DDIM;
    {
#pragma clang fp contract(off)
        float r[8];
#pragma unroll
        for (int j = 0; j < 8; ++j) r[j] = row[j] * row[j];
#pragma unroll
        for (int i = 1; i < 8; ++i) {
#pragma unroll
            for (int j = 0; j < 8; ++j) { float v = row[i * 8 + j]; r[j] += v * v; }
        }
        esq[k] = ((r[0] + r[1]) + (r[2] + r[3])) + ((r[4] + r[5]) + (r[6] + r[7]));
    }
#pragma unroll
    for (int d = 0; d < DDIM; ++d) {
        float v = row[d];
        unsigned short h = f2bf(v);
        Eh[k * DDIM + d] = h;
        El[k * DDIM + d] = f2bf(v - bf2f(h));
    }
}

// ---------------- MFMA approx scores + top-2 argmin (LDS-shared B) ----------------
// Block = 256 thr = 4 waves; 64 px/block (wave w: px w*16..w*16+15, all 1024 codes).
__global__ void __launch_bounds__(256, 4) gemm_kernel(const float* __restrict__ x,
                                                      const unsigned short* __restrict__ Eh,
                                                      const unsigned short* __restrict__ El,
                                                      const float* __restrict__ esq,
                                                      int* __restrict__ flag,
                                                      int* __restrict__ idx,
                                                      float* __restrict__ out) {
    __shared__ float x_lds[DDIM][64];          // 16KB
    __shared__ float esq_lds[KCODES];          // 4KB
    __shared__ unsigned char btile[2][4096];   // 8KB: dbuf B tile (Eh 2KB | El 2KB), swizzled

    const int tid = threadIdx.x;
    const int w = __builtin_amdgcn_readfirstlane(tid >> 6);
    const int l = tid & 63;
    const int g = l >> 4;              // 0..3
    const int col = l & 15;
    const int pxbase = blockIdx.x * 64;
    const int b = pxbase >> 10;
    const int p0 = pxbase & 1023;

    // stage x tile + esq
    {
        const float* xg = x + (size_t)b * 65536 + p0;
        for (int t = tid; t < DDIM * 64; t += 256)
            x_lds[t >> 6][t & 63] = xg[(size_t)(t >> 6) * 1024 + (t & 63)];
        for (int t = tid; t < KCODES; t += 256)
            esq_lds[t] = esq[t];
    }
    __syncthreads();

    // A fragments: row = col (px_local = w*16+col), k(d)-slot = g*8 + j (+32 per d-half)
    bf16x8 Ah0, Ah1, Al0, Al1;
    {
        const int pxl = w * 16 + col;
#pragma unroll
        for (int j = 0; j < 8; ++j) {
            float v0 = x_lds[g * 8 + j][pxl];
            unsigned short h0 = f2bf(v0);
            Ah0[j] = (short)h0;
            Al0[j] = (short)f2bf(v0 - bf2f(h0));
            float v1 = x_lds[32 + g * 8 + j][pxl];
            unsigned short h1 = f2bf(v1);
            Ah1[j] = (short)h1;
            Al1[j] = (short)f2bf(v1 - bf2f(h1));
        }
    }

    // B staging setup: thread covers 16B of the 4KB tile. tid<128 -> Eh half, else El.
    // Within a 2KB half: linear = u*16 (u=tid&127); code = u>>3, dchunk = (u&7)*16;
    // swizzle: dchunk ^= (code&7)<<4  (bijective within each 128B code-row).
    const unsigned short* src_base = (tid < 128) ? Eh : El;
    const int u = tid & 127;
    const int code_w = u >> 3;
    const int dst_off = ((tid >> 7) << 11) + (code_w << 7)
                      + (((u & 7) << 4) ^ ((code_w & 7) << 4));
    float4 stg;
    auto LD = [&](int t) {
        stg = *(const float4*)((const char*)src_base + (size_t)t * 2048 + (size_t)u * 16);
    };
    auto ST = [&](int t) {
        *(float4*)&btile[t & 1][dst_off] = stg;
    };

    // B read offsets (lane g,col): code-row col*128, d-chunk (g*16 / 64+g*16) ^ (col&7)<<4
    const int cx = (col & 7) << 4;
    const int rb = col << 7;
    const int oh0 = rb + ((g << 4) ^ cx);
    const int oh1 = rb + (((g << 4) + 64) ^ cx);

    float m1_0 = 3.4e38f, m1_1 = 3.4e38f, m1_2 = 3.4e38f, m1_3 = 3.4e38f;
    float m2_0 = 3.4e38f, m2_1 = 3.4e38f, m2_2 = 3.4e38f, m2_3 = 3.4e38f;
    int i1_0 = 0, i1_1 = 0, i1_2 = 0, i1_3 = 0;

    LD(0); ST(0);      // tile 0 staged (compiler inserts vmcnt before ds_write)
    LD(1);             // tile 1 in flight
    __syncthreads();

#pragma unroll 1
    for (int t = 0; t < NTILE; ++t) {
        // pipeline head: write tile t+1 (loaded last iter), issue load t+2.
        // buf[(t+1)&1] held tile t-1; all waves finished it before the last barrier.
        if (t + 1 < NTILE) ST(t + 1);
        if (t + 2 < NTILE) LD(t + 2);

        const unsigned char* bp = &btile[t & 1][0];
        const bf16x8 Bh0 = *(const bf16x8*)(bp + oh0);
        const bf16x8 Bh1 = *(const bf16x8*)(bp + oh1);
        const bf16x8 Bl0 = *(const bf16x8*)(bp + 2048 + oh0);
        const bf16x8 Bl1 = *(const bf16x8*)(bp + 2048 + oh1);

        // 3 independent 2-chains (hh, hl, lh), summed after — short critical path
        f32x4 a0 = {0.f, 0.f, 0.f, 0.f};
        f32x4 a1 = {0.f, 0.f, 0.f, 0.f};
        f32x4 a2 = {0.f, 0.f, 0.f, 0.f};
        a0 = __builtin_amdgcn_mfma_f32_16x16x32_bf16(Ah0, Bh0, a0, 0, 0, 0);
        a1 = __builtin_amdgcn_mfma_f32_16x16x32_bf16(Ah0, Bl0, a1, 0, 0, 0);
        a2 = __builtin_amdgcn_mfma_f32_16x16x32_bf16(Al0, Bh0, a2, 0, 0, 0);
        a0 = __builtin_amdgcn_mfma_f32_16x16x32_bf16(Ah1, Bh1, a0, 0, 0, 0);
        a1 = __builtin_amdgcn_mfma_f32_16x16x32_bf16(Ah1, Bl1, a1, 0, 0, 0);
        a2 = __builtin_amdgcn_mfma_f32_16x16x32_bf16(Al1, Bh1, a2, 0, 0, 0);

        const int kc = t * 16 + col;
        const float qe = esq_lds[t * 16 + col];
#define TOP2(R, M1, M2, I1)                                            \
        {                                                              \
            float d_ = (a0[R] + a1[R]) + a2[R];                        \
            float s_ = __builtin_fmaf(-2.0f, d_, qe);                  \
            float t_ = fmaxf(s_, M1);                                  \
            M2 = fminf(M2, t_);                                        \
            if (s_ < M1) I1 = kc;                                      \
            M1 = fminf(M1, s_);                                        \
        }
        TOP2(0, m1_0, m2_0, i1_0)
        TOP2(1, m1_1, m2_1, i1_1)
        TOP2(2, m1_2, m2_2, i1_2)
        TOP2(3, m1_3, m2_3, i1_3)
#undef TOP2
        __syncthreads();
    }

    // cross-lane merge over the 16 lanes of group g (same px rows)
#define MERGE(M1, M2, I1, R)                                                   \
    {                                                                          \
        float a1_ = M1, a2_ = M2; int j1 = I1;                                 \
        _Pragma("unroll")                                                      \
        for (int off = 1; off < 16; off <<= 1) {                               \
            float b1 = __shfl_xor(a1_, off);                                   \
            int jb = __shfl_xor(j1, off);                                      \
            float b2 = __shfl_xor(a2_, off);                                   \
            float hi = fmaxf(a1_, b1);                                         \
            a2_ = fminf(fminf(a2_, b2), hi);                                   \
            if (b1 < a1_) j1 = jb;                                             \
            a1_ = fminf(a1_, b1);                                              \
        }                                                                      \
        if (col == 0) {                                                        \
            int px = pxbase + w * 16 + g * 4 + (R);                            \
            flag[px] = (a2_ <= a1_ + MARGIN) ? 1 : 0;                          \
            idx[px] = j1;                                                      \
            out[IDX_OFF + px] = (float)j1;                                     \
        }                                                                      \
    }
    MERGE(m1_0, m2_0, i1_0, 0)
    MERGE(m1_1, m2_1, i1_1, 1)
    MERGE(m1_2, m2_2, i1_2, 2)
    MERGE(m1_3, m2_3, i1_3, 3)
#undef MERGE
}

// ---------------- cleanup: exact reference argmin, block-cooperative ----------------
__global__ void __launch_bounds__(256) cleanup_kernel(const float* __restrict__ x,
                                                      const float* __restrict__ e,
                                                      const float* __restrict__ esq,
                                                      const int* __restrict__ flag,
                                                      int* __restrict__ idx,
                                                      float* __restrict__ out) {
    __shared__ float xs[DDIM];
    __shared__ unsigned long long wmask[4];
    __shared__ float rbest[4];
    __shared__ int   ridx[4];

    const int tid = threadIdx.x;
    const int base = blockIdx.x * 256;

    unsigned long long m = __ballot(flag[base + tid] != 0);
    if ((tid & 63) == 0) wmask[tid >> 6] = m;
    __syncthreads();

#pragma unroll 1
    for (int seg = 0; seg < 4; ++seg) {
        unsigned long long mask = wmask[seg];   // uniform across block
        while (mask) {
            const int bit = __ffsll((long long)mask) - 1;
            mask &= mask - 1;
            const int p = base + seg * 64 + bit;

            if (tid < 64)
                xs[tid] = x[(size_t)(p >> 10) * 65536 + (size_t)tid * 1024 + (p & 1023)];
            __syncthreads();

            float xsq;
            {
#pragma clang fp contract(off)
                float r[8];
#pragma unroll
                for (int j = 0; j < 8; ++j) { float v = xs[j]; r[j] = v * v; }
#pragma unroll
                for (int ii = 1; ii < 8; ++ii) {
#pragma unroll
                    for (int j = 0; j < 8; ++j) { float v = xs[ii * 8 + j]; r[j] += v * v; }
                }
                xsq = ((r[0] + r[1]) + (r[2] + r[3])) + ((r[4] + r[5]) + (r[6] + r[7]));
            }

            float best = 3.4e38f;
            int bi = 0;
#pragma unroll
            for (int c = 0; c < 4; ++c) {
                const int k = tid * 4 + c;
                const float* er = e + (size_t)k * DDIM;
                float dt = 0.f;
#pragma unroll
                for (int d = 0; d < DDIM; ++d) dt = __builtin_fmaf(xs[d], er[d], dt);
                const float s = (xsq - 2.0f * dt) + esq[k];
                if (s < best) { best = s; bi = k; }
            }
#pragma unroll
            for (int off = 1; off < 64; off <<= 1) {
                float b2 = __shfl_xor(best, off);
                int k2 = __shfl_xor(bi, off);
                if (b2 < best || (b2 == best && k2 < bi)) { best = b2; bi = k2; }
            }
            if ((tid & 63) == 0) { rbest[tid >> 6] = best; ridx[tid >> 6] = bi; }
            __syncthreads();
            if (tid == 0) {
                float bb = rbest[0]; int bj = ridx[0];
#pragma unroll
                for (int c2 = 1; c2 < 4; ++c2) {
                    if (rbest[c2] < bb || (rbest[c2] == bb && ridx[c2] < bj)) {
                        bb = rbest[c2]; bj = ridx[c2];
                    }
                }
                idx[p] = bj;
                out[IDX_OFF + p] = (float)bj;
            }
            __syncthreads();
        }
    }
}

// ---------------- gather + transpose + per-block loss partials ----------------
__global__ void __launch_bounds__(256) gather_kernel(const float* __restrict__ x,
                                                     const float* __restrict__ e,
                                                     const int* __restrict__ idx,
                                                     float* __restrict__ out,
                                                     float* __restrict__ partial) {
    const int bd = blockIdx.x;          // = b*64 + d
    const int b = bd >> 6;
    const int d = bd & 63;
    const size_t base = (size_t)bd * 1024;
    const int* idxb = idx + b * 1024;

    float acc = 0.f;
#pragma unroll
    for (int j = 0; j < 4; ++j) {
        int p = threadIdx.x + j * 256;
        int k = idxb[p];
        float ev = e[k * 64 + d];
        float xv = x[base + p];
        out[1 + base + p] = ev;
        float df = ev - xv;
        acc = __builtin_fmaf(df, df, acc);
    }
    __shared__ float sm[256];
    sm[threadIdx.x] = acc;
    __syncthreads();
    for (int s = 128; s > 0; s >>= 1) {
        if (threadIdx.x < s) sm[threadIdx.x] += sm[threadIdx.x + s];
        __syncthreads();
    }
    if (threadIdx.x == 0) partial[bd] = sm[0];
}

__global__ void __launch_bounds__(256) loss_kernel(const float* __restrict__ partial,
                                                   float* __restrict__ out) {
    float acc = 0.f;
    for (int i = threadIdx.x; i < 4096; i += 256) acc += partial[i];
    __shared__ float sm[256];
    sm[threadIdx.x] = acc;
    __syncthreads();
    for (int s = 128; s > 0; s >>= 1) {
        if (threadIdx.x < s) sm[threadIdx.x] += sm[threadIdx.x + s];
        __syncthreads();
    }
    if (threadIdx.x == 0) out[0] = sm[0] * (1.25f / 4194304.f);
}

extern "C" void kernel_launch(void* const* d_in, const int* in_sizes, int n_in,
                              void* d_out, int out_size, void* d_ws, size_t ws_size,
                              hipStream_t stream) {
    const float* x = (const float*)d_in[0];   // [64,64,32,32]
    const float* e = (const float*)d_in[1];   // [1024,64]
    float* out = (float*)d_out;

    // ws: esq 4KB | Eh 128KB | El 128KB | flag 256KB | idx 256KB | partial 16KB
    char* wsb = (char*)d_ws;
    float*          esq     = (float*)wsb;
    unsigned short* Eh      = (unsigned short*)(wsb + 4096);
    unsigned short* El      = (unsigned short*)(wsb + 4096 + 131072);
    int*            flag    = (int*)(wsb + 4096 + 2 * 131072);
    int*            idx     = (int*)(wsb + 4096 + 2 * 131072 + NPIX * 4);
    float*          partial = (float*)(wsb + 4096 + 2 * 131072 + 2 * NPIX * 4);

    esplit_kernel<<<4, 256, 0, stream>>>(e, esq, Eh, El);
    gemm_kernel<<<NPIX / 64, 256, 0, stream>>>(x, Eh, El, esq, flag, idx, out);
    cleanup_kernel<<<NPIX / 256, 256, 0, stream>>>(x, e, esq, flag, idx, out);
    gather_kernel<<<4096, 256, 0, stream>>>(x, e, idx, out, partial);
    loss_kernel<<<1, 256, 0, stream>>>(partial, out);
}